// Round 2
// baseline (211.995 us; speedup 1.0000x reference)
//
#include <hip/hip_runtime.h>
#include <math.h>

#define TILE 16

// Pass 1: append each rect's index into the list of every 16x16-cell tile its
// cell patch touches (span <= 4 cells/axis => 1..4 tiles).
__global__ void build_bins(const float* __restrict__ boundary,
                           const float2* __restrict__ xy,
                           const float2* __restrict__ dims,
                           int* __restrict__ cnt,
                           int* __restrict__ lists,
                           int cap, int G, int tilesX, int n_rects)
{
    int n = blockIdx.x * blockDim.x + threadIdx.x;
    if (n >= n_rects) return;

    float xmin = boundary[0], ymin = boundary[1];
    float xmax = boundary[2], ymax = boundary[3];
    float inv_lx = (float)G / (xmax - xmin);
    float inv_ly = (float)G / (ymax - ymin);

    float2 p = xy[n];
    float2 d = dims[n];
    int i0 = (int)floorf((p.x       - xmin) * inv_lx);
    int i1 = (int)floorf((p.x + d.x - xmin) * inv_lx);
    int j0 = (int)floorf((p.y       - ymin) * inv_ly);
    int j1 = (int)floorf((p.y + d.y - ymin) * inv_ly);
    i0 = max(i0, 0); i1 = min(i1, G - 1);
    j0 = max(j0, 0); j1 = min(j1, G - 1);
    if (i0 > i1 || j0 > j1) return;

    int ti0 = i0 / TILE, ti1 = i1 / TILE;
    int tj0 = j0 / TILE, tj1 = j1 / TILE;
    for (int ti = ti0; ti <= ti1; ++ti) {
        for (int tj = tj0; tj <= tj1; ++tj) {
            int t = ti * tilesX + tj;
            int pos = atomicAdd(&cnt[t], 1);
            if (pos < cap) lists[(size_t)t * cap + pos] = n;
        }
    }
}

// Pass 2: one block per 16x16 output tile. Accumulate the tile in LDS with
// LDS atomics, then write out coalesced, non-atomic (each cell owned by
// exactly one block -> no output memset needed).
__global__ __launch_bounds__(TILE * TILE)
void gather_tiles(const float* __restrict__ boundary,
                  const float2* __restrict__ xy,
                  const float2* __restrict__ dims,
                  const float* __restrict__ w,
                  const int* __restrict__ cnt,
                  const int* __restrict__ lists,
                  float* __restrict__ out,
                  int cap, int G, int tilesX)
{
    __shared__ float acc[TILE][TILE];
    int t   = blockIdx.x;
    int tid = threadIdx.x;            // 256 threads = 16x16
    int r   = tid >> 4, c = tid & 15;
    int ci0 = (t / tilesX) * TILE;    // first cell row of this tile
    int cj0 = (t % tilesX) * TILE;    // first cell col

    acc[r][c] = 0.0f;
    __syncthreads();

    float xmin = boundary[0], ymin = boundary[1];
    float xmax = boundary[2], ymax = boundary[3];
    float lx = (xmax - xmin) / (float)G;
    float ly = (ymax - ymin) / (float)G;
    // Same formulas as build_bins so floor-indexing is bit-identical.
    float inv_lx = (float)G / (xmax - xmin);
    float inv_ly = (float)G / (ymax - ymin);
    float inv_area = inv_lx * inv_ly;

    int m = min(cnt[t], cap);
    for (int e = tid; e < m; e += TILE * TILE) {
        int rid = lists[(size_t)t * cap + e];
        float2 p = xy[rid];
        float2 d = dims[rid];
        float bx0 = p.x, bx1 = p.x + d.x;
        float by0 = p.y, by1 = p.y + d.y;
        float cw = w[rid] * inv_area;

        int i0 = max((int)floorf((bx0 - xmin) * inv_lx), ci0);
        int i1 = min((int)floorf((bx1 - xmin) * inv_lx), ci0 + TILE - 1);
        i1 = min(i1, G - 1);
        int j0 = max((int)floorf((by0 - ymin) * inv_ly), cj0);
        int j1 = min((int)floorf((by1 - ymin) * inv_ly), cj0 + TILE - 1);
        j1 = min(j1, G - 1);

        for (int i = i0; i <= i1; ++i) {
            float gx0 = xmin + (float)i * lx;
            float ox  = fminf(gx0 + lx, bx1) - fmaxf(gx0, bx0);
            if (ox <= 0.0f) continue;
            float cox = cw * ox;
            for (int j = j0; j <= j1; ++j) {
                float gy0 = ymin + (float)j * ly;
                float oy  = fminf(gy0 + ly, by1) - fmaxf(gy0, by0);
                if (oy > 0.0f) {
                    atomicAdd(&acc[i - ci0][j - cj0], cox * oy);
                }
            }
        }
    }
    __syncthreads();

    out[(size_t)(ci0 + r) * G + cj0 + c] = acc[r][c];
}

// Fallback (general G / tiny ws): direct global-atomic scatter (round-1 kernel).
__global__ void scatter_direct(const float* __restrict__ boundary,
                               const float2* __restrict__ xy,
                               const float2* __restrict__ dims,
                               const float* __restrict__ w,
                               float* __restrict__ out,
                               int G, int n_rects)
{
    int n = blockIdx.x * blockDim.x + threadIdx.x;
    if (n >= n_rects) return;
    float xmin = boundary[0], ymin = boundary[1];
    float xmax = boundary[2], ymax = boundary[3];
    float lx = (xmax - xmin) / (float)G;
    float ly = (ymax - ymin) / (float)G;
    float2 p = xy[n]; float2 d = dims[n];
    float bx0 = p.x, by0 = p.y, bx1 = bx0 + d.x, by1 = by0 + d.y;
    float cw = w[n] / (lx * ly);
    int i0 = max((int)floorf((bx0 - xmin) / lx), 0);
    int i1 = min((int)floorf((bx1 - xmin) / lx), G - 1);
    int j0 = max((int)floorf((by0 - ymin) / ly), 0);
    int j1 = min((int)floorf((by1 - ymin) / ly), G - 1);
    for (int i = i0; i <= i1; ++i) {
        float gx0 = xmin + (float)i * lx;
        float ox = fmaxf(fminf(gx0 + lx, bx1) - fmaxf(gx0, bx0), 0.0f);
        if (ox <= 0.0f) continue;
        float cox = cw * ox;
        for (int j = j0; j <= j1; ++j) {
            float gy0 = ymin + (float)j * ly;
            float oy = fmaxf(fminf(gy0 + ly, by1) - fmaxf(gy0, by0), 0.0f);
            if (oy > 0.0f) atomicAdd(out + (size_t)i * G + j, cox * oy);
        }
    }
}

extern "C" void kernel_launch(void* const* d_in, const int* in_sizes, int n_in,
                              void* d_out, int out_size, void* d_ws, size_t ws_size,
                              hipStream_t stream) {
    const float*  boundary = (const float*)d_in[0];
    const float2* xy       = (const float2*)d_in[1];
    const float2* dims     = (const float2*)d_in[2];
    const float*  cweight  = (const float*)d_in[3];
    float* out = (float*)d_out;
    int n_rects = in_sizes[1] / 2;

    int G = (int)lround(sqrt((double)out_size));
    bool shape_ok = ((long long)G * G == (long long)out_size) && (G % TILE == 0);

    int tilesX = shape_ok ? (G / TILE) : 1;
    int numTiles = tilesX * tilesX;
    int cap = 2048;
    size_t need = (size_t)numTiles * sizeof(int) + (size_t)numTiles * cap * sizeof(int);
    if (need > ws_size && numTiles > 0) {
        cap = (int)((ws_size / sizeof(int) - numTiles) / (size_t)numTiles);
    }

    const int block = 256;
    if (shape_ok && cap >= 512) {
        int* cnt   = (int*)d_ws;
        int* lists = cnt + numTiles;
        hipMemsetAsync(cnt, 0, (size_t)numTiles * sizeof(int), stream);
        build_bins<<<(n_rects + block - 1) / block, block, 0, stream>>>(
            boundary, xy, dims, cnt, lists, cap, G, tilesX, n_rects);
        gather_tiles<<<numTiles, TILE * TILE, 0, stream>>>(
            boundary, xy, dims, cweight, cnt, lists, out, cap, G, tilesX);
    } else {
        hipMemsetAsync(out, 0, (size_t)out_size * sizeof(float), stream);
        scatter_direct<<<(n_rects + block - 1) / block, block, 0, stream>>>(
            boundary, xy, dims, cweight, out, G, n_rects);
    }
}

// Round 3
// 108.836 us; speedup vs baseline: 1.9479x; 1.9479x over previous
//
#include <hip/hip_runtime.h>
#include <math.h>

#define TILE 16
#define OCAP 1024   // overflow safety-net entries (tile,rid pairs)

// ---------------------------------------------------------------------------
// Pass 1: K blocks, each owning a PRIVATE per-tile sub-list region.
// Counting uses LDS atomics only; list emission is plain (cached) global
// stores. No global atomics except the (expected-empty) overflow net.
// ---------------------------------------------------------------------------
__global__ __launch_bounds__(1024)
void bin_private(const float* __restrict__ boundary,
                 const float2* __restrict__ xy,
                 const float2* __restrict__ dims,
                 int* __restrict__ cnt,      // [K * numTiles]
                 int* __restrict__ lists,    // [K * numTiles * cap]
                 int* __restrict__ ocnt,     // [1]
                 int* __restrict__ olist,    // [2 * OCAP] (tile, rid) pairs
                 int cap, int G, int tilesX, int numTiles,
                 int n_rects, int K)
{
    __shared__ int lds_cnt[1024];            // numTiles <= 1024 enforced by host
    const int k   = blockIdx.x;
    const int tid = threadIdx.x;

    for (int t = tid; t < numTiles; t += blockDim.x) lds_cnt[t] = 0;
    __syncthreads();

    const int chunk = (n_rects + K - 1) / K;
    const int r0 = k * chunk;
    const int r1 = min(r0 + chunk, n_rects);

    const float xmin = boundary[0], ymin = boundary[1];
    const float xmax = boundary[2], ymax = boundary[3];
    const float inv_lx = (float)G / (xmax - xmin);
    const float inv_ly = (float)G / (ymax - ymin);

    for (int n = r0 + tid; n < r1; n += blockDim.x) {
        float2 p = xy[n];
        float2 d = dims[n];
        int i0 = (int)floorf((p.x       - xmin) * inv_lx);
        int i1 = (int)floorf((p.x + d.x - xmin) * inv_lx);
        int j0 = (int)floorf((p.y       - ymin) * inv_ly);
        int j1 = (int)floorf((p.y + d.y - ymin) * inv_ly);
        i0 = max(i0, 0); i1 = min(i1, G - 1);
        j0 = max(j0, 0); j1 = min(j1, G - 1);
        if (i0 > i1 || j0 > j1) continue;

        int ti0 = i0 / TILE, ti1 = i1 / TILE;
        int tj0 = j0 / TILE, tj1 = j1 / TILE;
        for (int ti = ti0; ti <= ti1; ++ti) {
            for (int tj = tj0; tj <= tj1; ++tj) {
                int t   = ti * tilesX + tj;
                int pos = atomicAdd(&lds_cnt[t], 1);      // LDS atomic: cheap
                if (pos < cap) {
                    lists[((size_t)k * numTiles + t) * cap + pos] = n;
                } else {
                    int op = atomicAdd(ocnt, 1);          // expected ~never
                    if (op < OCAP) { olist[2 * op] = t; olist[2 * op + 1] = n; }
                }
            }
        }
    }
    __syncthreads();
    for (int t = tid; t < numTiles; t += blockDim.x)
        cnt[k * numTiles + t] = min(lds_cnt[t], cap);
}

// ---------------------------------------------------------------------------
// Pass 2: one 1024-thread block per 16x16 output tile. LDS-atomic accumulate,
// then coalesced non-atomic output write (each cell owned by one block).
// ---------------------------------------------------------------------------
__global__ __launch_bounds__(1024)
void gather_tiles(const float* __restrict__ boundary,
                  const float2* __restrict__ xy,
                  const float2* __restrict__ dims,
                  const float* __restrict__ w,
                  const int* __restrict__ cnt,
                  const int* __restrict__ lists,
                  const int* __restrict__ ocnt,
                  const int* __restrict__ olist,
                  float* __restrict__ out,
                  int cap, int G, int tilesX, int numTiles, int K)
{
    __shared__ float acc[TILE * TILE];
    __shared__ int   pref[129];              // K <= 128
    const int t   = blockIdx.x;
    const int tid = threadIdx.x;
    const int ci0 = (t / tilesX) * TILE;
    const int cj0 = (t % tilesX) * TILE;

    if (tid < TILE * TILE) acc[tid] = 0.0f;
    if (tid == 0) {
        int s = 0; pref[0] = 0;
        for (int k = 0; k < K; ++k) { s += cnt[k * numTiles + t]; pref[k + 1] = s; }
    }
    __syncthreads();
    const int m = pref[K];

    const float xmin = boundary[0], ymin = boundary[1];
    const float xmax = boundary[2], ymax = boundary[3];
    const float lx = (xmax - xmin) / (float)G;
    const float ly = (ymax - ymin) / (float)G;
    const float inv_lx = (float)G / (xmax - xmin);   // bit-identical to pass 1
    const float inv_ly = (float)G / (ymax - ymin);
    const float inv_area = inv_lx * inv_ly;

    for (int e = tid; e < m; e += blockDim.x) {
        int lo = 0, hi = K;                  // pref[lo] <= e < pref[lo+1]
        while (hi - lo > 1) { int mid = (lo + hi) >> 1; if (pref[mid] <= e) lo = mid; else hi = mid; }
        int rid = lists[((size_t)lo * numTiles + t) * cap + (e - pref[lo])];

        float2 p = xy[rid];
        float2 d = dims[rid];
        float bx0 = p.x, bx1 = p.x + d.x;
        float by0 = p.y, by1 = p.y + d.y;
        float cw = w[rid] * inv_area;

        int i0 = max((int)floorf((bx0 - xmin) * inv_lx), ci0);
        int i1 = min(min((int)floorf((bx1 - xmin) * inv_lx), ci0 + TILE - 1), G - 1);
        int j0 = max((int)floorf((by0 - ymin) * inv_ly), cj0);
        int j1 = min(min((int)floorf((by1 - ymin) * inv_ly), cj0 + TILE - 1), G - 1);

        for (int i = i0; i <= i1; ++i) {
            float gx0 = xmin + (float)i * lx;
            float ox  = fminf(gx0 + lx, bx1) - fmaxf(gx0, bx0);
            if (ox <= 0.0f) continue;
            float cox = cw * ox;
            for (int j = j0; j <= j1; ++j) {
                float gy0 = ymin + (float)j * ly;
                float oy  = fminf(gy0 + ly, by1) - fmaxf(gy0, by0);
                if (oy > 0.0f)
                    atomicAdd(&acc[(i - ci0) * TILE + (j - cj0)], cox * oy);
            }
        }
    }

    // Overflow net (expected empty).
    int oc = min(*ocnt, OCAP);
    for (int e = tid; e < oc; e += blockDim.x) {
        if (olist[2 * e] != t) continue;
        int rid = olist[2 * e + 1];
        float2 p = xy[rid];
        float2 d = dims[rid];
        float bx0 = p.x, bx1 = p.x + d.x;
        float by0 = p.y, by1 = p.y + d.y;
        float cw = w[rid] * inv_area;
        int i0 = max((int)floorf((bx0 - xmin) * inv_lx), ci0);
        int i1 = min(min((int)floorf((bx1 - xmin) * inv_lx), ci0 + TILE - 1), G - 1);
        int j0 = max((int)floorf((by0 - ymin) * inv_ly), cj0);
        int j1 = min(min((int)floorf((by1 - ymin) * inv_ly), cj0 + TILE - 1), G - 1);
        for (int i = i0; i <= i1; ++i) {
            float gx0 = xmin + (float)i * lx;
            float ox  = fminf(gx0 + lx, bx1) - fmaxf(gx0, bx0);
            if (ox <= 0.0f) continue;
            float cox = cw * ox;
            for (int j = j0; j <= j1; ++j) {
                float gy0 = ymin + (float)j * ly;
                float oy  = fminf(gy0 + ly, by1) - fmaxf(gy0, by0);
                if (oy > 0.0f)
                    atomicAdd(&acc[(i - ci0) * TILE + (j - cj0)], cox * oy);
            }
        }
    }
    __syncthreads();

    if (tid < TILE * TILE) {
        int r = tid >> 4, c = tid & 15;
        out[(size_t)(ci0 + r) * G + cj0 + c] = acc[tid];
    }
}

// ---------------------------------------------------------------------------
// Fallback for odd shapes / tiny workspace: direct global-atomic scatter.
// ---------------------------------------------------------------------------
__global__ void scatter_direct(const float* __restrict__ boundary,
                               const float2* __restrict__ xy,
                               const float2* __restrict__ dims,
                               const float* __restrict__ w,
                               float* __restrict__ out,
                               int G, int n_rects)
{
    int n = blockIdx.x * blockDim.x + threadIdx.x;
    if (n >= n_rects) return;
    float xmin = boundary[0], ymin = boundary[1];
    float xmax = boundary[2], ymax = boundary[3];
    float lx = (xmax - xmin) / (float)G;
    float ly = (ymax - ymin) / (float)G;
    float2 p = xy[n]; float2 d = dims[n];
    float bx0 = p.x, by0 = p.y, bx1 = bx0 + d.x, by1 = by0 + d.y;
    float cw = w[n] / (lx * ly);
    int i0 = max((int)floorf((bx0 - xmin) / lx), 0);
    int i1 = min((int)floorf((bx1 - xmin) / lx), G - 1);
    int j0 = max((int)floorf((by0 - ymin) / ly), 0);
    int j1 = min((int)floorf((by1 - ymin) / ly), G - 1);
    for (int i = i0; i <= i1; ++i) {
        float gx0 = xmin + (float)i * lx;
        float ox = fmaxf(fminf(gx0 + lx, bx1) - fmaxf(gx0, bx0), 0.0f);
        if (ox <= 0.0f) continue;
        float cox = cw * ox;
        for (int j = j0; j <= j1; ++j) {
            float gy0 = ymin + (float)j * ly;
            float oy = fmaxf(fminf(gy0 + ly, by1) - fmaxf(gy0, by0), 0.0f);
            if (oy > 0.0f) atomicAdd(out + (size_t)i * G + j, cox * oy);
        }
    }
}

extern "C" void kernel_launch(void* const* d_in, const int* in_sizes, int n_in,
                              void* d_out, int out_size, void* d_ws, size_t ws_size,
                              hipStream_t stream) {
    const float*  boundary = (const float*)d_in[0];
    const float2* xy       = (const float2*)d_in[1];
    const float2* dims     = (const float2*)d_in[2];
    const float*  cweight  = (const float*)d_in[3];
    float* out = (float*)d_out;
    const int n_rects = in_sizes[1] / 2;

    int G = (int)lround(sqrt((double)out_size));
    const int tilesX   = (G > 0) ? (G / TILE) : 0;
    const int numTiles = tilesX * tilesX;
    const bool shape_ok = ((long long)G * G == (long long)out_size) &&
                          (G % TILE == 0) && numTiles > 0 && numTiles <= 1024;

    // Pick largest K (private-bin parallelism) whose per-bin capacity keeps a
    // >=4-sigma headroom over the expected per-bin count (~1.3 entries/rect
    // spread over K*numTiles bins). Overflow list backstops the tail.
    int K = 0, cap = 0;
    if (shape_ok) {
        const int kcand[5] = {128, 64, 32, 16, 8};
        const long long ws_ints = (long long)(ws_size / 4);
        for (int ci = 0; ci < 5; ++ci) {
            int k = kcand[ci];
            long long fixed = (long long)k * numTiles + 2 + 2 * OCAP;
            if (ws_ints <= fixed) continue;
            long long capf = (ws_ints - fixed) / ((long long)k * numTiles);
            double mean = 1.30 * (double)n_rects / ((double)k * numTiles);
            int need = (int)(mean + 4.0 * sqrt(mean) + 6.0) + 1;
            if (capf >= need) {
                K = k;
                long long c = capf < (long long)(4 * need) ? capf : (long long)(4 * need);
                cap = (int)c;
                break;
            }
        }
    }

    if (K > 0) {
        int* wsI   = (int*)d_ws;
        int* cnt   = wsI;                       // K * numTiles
        int* ocnt  = cnt + (size_t)K * numTiles;
        int* olist = ocnt + 2;                  // 2*OCAP ints
        int* lists = olist + 2 * OCAP;

        hipMemsetAsync(ocnt, 0, sizeof(int), stream);
        bin_private<<<K, 1024, 0, stream>>>(
            boundary, xy, dims, cnt, lists, ocnt, olist,
            cap, G, tilesX, numTiles, n_rects, K);
        gather_tiles<<<numTiles, 1024, 0, stream>>>(
            boundary, xy, dims, cweight, cnt, lists, ocnt, olist, out,
            cap, G, tilesX, numTiles, K);
    } else {
        hipMemsetAsync(out, 0, (size_t)out_size * sizeof(float), stream);
        const int block = 256;
        scatter_direct<<<(n_rects + block - 1) / block, block, 0, stream>>>(
            boundary, xy, dims, cweight, out, G, n_rects);
    }
}

// Round 4
// 82.865 us; speedup vs baseline: 2.5583x; 1.3134x over previous
//
#include <hip/hip_runtime.h>
#include <math.h>

// ---------------------------------------------------------------------------
// Strip-scan with replication: block b = s*R + r owns row-strip s (rows rows
// of the G x G field, held in LDS) and scans rect-subset r (contiguous,
// coalesced). Rects touching the strip (<=4-row patch) are accumulated with
// LDS atomics only. The full strip (zeros included) is then written to ws,
// so ws needs no zero-init and there are NO global atomics anywhere.
// ---------------------------------------------------------------------------
__global__ __launch_bounds__(1024)
void strip_scan(const float* __restrict__ boundary,
                const float2* __restrict__ xy,
                const float2* __restrict__ dims,
                const float* __restrict__ w,
                float* __restrict__ ws,
                int G, int R, int rows, int n_rects)
{
    extern __shared__ float acc[];           // rows * G floats
    const int b   = blockIdx.x;
    const int s   = b / R;                   // strip index
    const int r   = b % R;                   // rect-subset index
    const int tid = threadIdx.x;
    const int stripElems = rows * G;
    const int row0 = s * rows;
    const int row1 = row0 + rows - 1;

    for (int c = tid; c < stripElems; c += blockDim.x) acc[c] = 0.0f;
    __syncthreads();

    const float xmin = boundary[0], ymin = boundary[1];
    const float xmax = boundary[2], ymax = boundary[3];
    const float lx = (xmax - xmin) / (float)G;
    const float ly = (ymax - ymin) / (float)G;
    const float inv_lx = (float)G / (xmax - xmin);
    const float inv_ly = (float)G / (ymax - ymin);
    const float inv_area = inv_lx * inv_ly;

    const int chunk = (n_rects + R - 1) / R;
    const int lo = r * chunk;
    const int hi = min(lo + chunk, n_rects);

    for (int n = lo + tid; n < hi; n += blockDim.x) {
        float2 p = xy[n];
        float2 d = dims[n];
        const float bx0 = p.x, bx1 = p.x + d.x;

        int i0 = (int)floorf((bx0 - xmin) * inv_lx);
        int i1 = (int)floorf((bx1 - xmin) * inv_lx);
        i0 = max(max(i0, 0), row0);
        i1 = min(min(i1, G - 1), row1);
        if (i0 > i1) continue;                        // doesn't touch this strip

        const float by0 = p.y, by1 = p.y + d.y;
        int j0 = max((int)floorf((by0 - ymin) * inv_ly), 0);
        int j1 = min((int)floorf((by1 - ymin) * inv_ly), G - 1);
        if (j0 > j1) continue;

        const float cw = w[n] * inv_area;

        for (int i = i0; i <= i1; ++i) {
            float gx0 = xmin + (float)i * lx;
            float ox  = fminf(gx0 + lx, bx1) - fmaxf(gx0, bx0);
            if (ox <= 0.0f) continue;
            float cox = cw * ox;
            float* rowp = acc + (i - row0) * G;
            for (int j = j0; j <= j1; ++j) {
                float gy0 = ymin + (float)j * ly;
                float oy  = fminf(gy0 + ly, by1) - fmaxf(gy0, by0);
                if (oy > 0.0f)
                    atomicAdd(rowp + j, cox * oy);    // LDS atomic: on-CU, cheap
            }
        }
    }
    __syncthreads();

    // Coalesced full-strip writeout (includes zeros -> ws needs no memset).
    float* dst = ws + (size_t)b * stripElems;
    for (int c = tid; c < stripElems; c += blockDim.x) dst[c] = acc[c];
}

// ---------------------------------------------------------------------------
// Reduce the R replicas of each strip into the output. Coalesced reads
// (stride stripElems between replicas), coalesced writes, no atomics.
// ---------------------------------------------------------------------------
__global__ __launch_bounds__(256)
void reduce_strips(const float* __restrict__ ws,
                   float* __restrict__ out,
                   int G, int R, int rows)
{
    const int c = blockIdx.x * blockDim.x + threadIdx.x;
    if (c >= G * G) return;
    const int i = c / G;
    const int j = c - i * G;
    const int s = i / rows;
    const int stripElems = rows * G;
    const int local = (i - s * rows) * G + j;

    const float* base = ws + (size_t)s * R * stripElems + local;
    float sum = 0.0f;
    #pragma unroll 8
    for (int r = 0; r < R; ++r)
        sum += base[(size_t)r * stripElems];
    out[c] = sum;
}

// ---------------------------------------------------------------------------
// Fallback for odd shapes / tiny workspace: direct global-atomic scatter.
// ---------------------------------------------------------------------------
__global__ void scatter_direct(const float* __restrict__ boundary,
                               const float2* __restrict__ xy,
                               const float2* __restrict__ dims,
                               const float* __restrict__ w,
                               float* __restrict__ out,
                               int G, int n_rects)
{
    int n = blockIdx.x * blockDim.x + threadIdx.x;
    if (n >= n_rects) return;
    float xmin = boundary[0], ymin = boundary[1];
    float xmax = boundary[2], ymax = boundary[3];
    float lx = (xmax - xmin) / (float)G;
    float ly = (ymax - ymin) / (float)G;
    float2 p = xy[n]; float2 d = dims[n];
    float bx0 = p.x, by0 = p.y, bx1 = bx0 + d.x, by1 = by0 + d.y;
    float cw = w[n] / (lx * ly);
    int i0 = max((int)floorf((bx0 - xmin) / lx), 0);
    int i1 = min((int)floorf((bx1 - xmin) / lx), G - 1);
    int j0 = max((int)floorf((by0 - ymin) / ly), 0);
    int j1 = min((int)floorf((by1 - ymin) / ly), G - 1);
    for (int i = i0; i <= i1; ++i) {
        float gx0 = xmin + (float)i * lx;
        float ox = fmaxf(fminf(gx0 + lx, bx1) - fmaxf(gx0, bx0), 0.0f);
        if (ox <= 0.0f) continue;
        float cox = cw * ox;
        for (int j = j0; j <= j1; ++j) {
            float gy0 = ymin + (float)j * ly;
            float oy = fmaxf(fminf(gy0 + ly, by1) - fmaxf(gy0, by0), 0.0f);
            if (oy > 0.0f) atomicAdd(out + (size_t)i * G + j, cox * oy);
        }
    }
}

extern "C" void kernel_launch(void* const* d_in, const int* in_sizes, int n_in,
                              void* d_out, int out_size, void* d_ws, size_t ws_size,
                              hipStream_t stream) {
    const float*  boundary = (const float*)d_in[0];
    const float2* xy       = (const float2*)d_in[1];
    const float2* dims     = (const float2*)d_in[2];
    const float*  cweight  = (const float*)d_in[3];
    float* out = (float*)d_out;
    const int n_rects = in_sizes[1] / 2;

    int G = (int)lround(sqrt((double)out_size));
    const bool square = ((long long)G * G == (long long)out_size) && G > 0;

    // Pick smallest strip count S (power of 2, dividing G) whose strip fits
    // in 64 KB of LDS; then R replicas so S*R covers the chip and ws fits.
    int S = 0, rows = 0;
    if (square) {
        for (int cand = 1; cand <= 64; cand <<= 1) {
            if (G % cand) continue;
            long long bytes = (long long)(G / cand) * G * 4;
            if (bytes <= 64 * 1024) { S = cand; rows = G / cand; break; }
        }
    }
    int R = 0;
    if (S > 0) {
        R = 256 / S;                         // S*R = 256 blocks = 1/CU
        if (R < 1) R = 1;
        long long need = (long long)S * R * rows * G * 4;
        while (R > 1 && need > (long long)ws_size) {
            R >>= 1;
            need = (long long)S * R * rows * G * 4;
        }
        if (need > (long long)ws_size) R = 0;
    }

    if (R > 0) {
        float* ws = (float*)d_ws;
        const int stripBytes = rows * G * 4;
        strip_scan<<<S * R, 1024, stripBytes, stream>>>(
            boundary, xy, dims, cweight, ws, G, R, rows, n_rects);
        reduce_strips<<<(G * G + 255) / 256, 256, 0, stream>>>(
            ws, out, G, R, rows);
    } else {
        hipMemsetAsync(out, 0, (size_t)out_size * sizeof(float), stream);
        const int block = 256;
        scatter_direct<<<(n_rects + block - 1) / block, block, 0, stream>>>(
            boundary, xy, dims, cweight, out, G, n_rects);
    }
}